// Round 5
// baseline (14448.563 us; speedup 1.0000x reference)
//
#include <hip/hip_runtime.h>

#define B_TOT 128
#define T_LEN 800
#define I_DIM 9
#define H_DIM 1024
#define O_DIM 8
#define NB    16            // batches per group (one M=16 MFMA tile)
#define NSLC  8             // blocks per group (N-split)
#define NCOL  128           // output columns per block (8 waves x 16)
#define GROUPS (B_TOT / NB) // 8

typedef float f32x4 __attribute__((ext_vector_type(4)));
typedef short s16x8 __attribute__((ext_vector_type(8)));
typedef unsigned long long u64;

__device__ __forceinline__ unsigned short f2bf(float f) {
    unsigned u = __float_as_uint(f);
    u += 0x7fffu + ((u >> 16) & 1u);   // round-to-nearest-even
    return (unsigned short)(u >> 16);
}

__device__ __forceinline__ s16x8 mk(u64 lo, u64 hi) {
    union { u64 q[2]; s16x8 v; } u;
    u.q[0] = lo; u.q[1] = hi;
    return u.v;
}

#define AL(p) __hip_atomic_load((p), __ATOMIC_RELAXED, __HIP_MEMORY_SCOPE_AGENT)

// -------- recurrent scan: 64 blocks (8 groups x 8 N-slices), ZERO barriers --
// Every wave is an independent pipeline stage. Per-wave flags (64/group) let a
// consumer wave start MFMA on k-chunk q as soon as producer block q's 8 waves
// have published -- no __syncthreads, no LDS, no cooperative gather. A-frags
// are direct 16B reads from the [b][k] hx layout (relaxed agent atomics, L3).
__global__ __launch_bounds__(512, 2)
void rnn_scan(const float* __restrict__ x,        // [B][T][9]
              const float* __restrict__ noise,    // [B][T][H]
              const float* __restrict__ Win,      // [H][9]
              const float* __restrict__ Wrec,     // [H][H] f32, row n = out col
              unsigned short* __restrict__ hx,    // [G][2][NB][H] bf16 exchange
              unsigned* __restrict__ flags,       // [G][64 producer-waves] stride-8
              float* __restrict__ hiddens)        // [B][T][H] f32 out
{
    const int tid  = threadIdx.x;
    const int lane = tid & 63;
    const int w    = tid >> 6;          // wave 0..7, owns 16 columns
    const int g    = blockIdx.x & 7;    // group (same-XCD affinity heuristic)
    const int s    = blockIdx.x >> 3;   // N-slice 0..7
    const int b0   = g * NB;
    const int l15  = lane & 15;
    const int kb   = lane >> 4;
    const int n    = s * NCOL + w * 16 + l15;   // this lane's output column

    // ---- prologue: Wrec row n -> bf16 B-fragments in registers (128 VGPR) --
    s16x8 breg[32];
    {
        const float* wrow = Wrec + (size_t)n * H_DIM + kb * 8;
#pragma unroll
        for (int kt = 0; kt < 32; ++kt) {
            float4 v0 = *(const float4*)(wrow + kt * 32);
            float4 v1 = *(const float4*)(wrow + kt * 32 + 4);
            union { s16x8 v; unsigned short u[8]; } r;
            r.u[0] = f2bf(v0.x); r.u[1] = f2bf(v0.y); r.u[2] = f2bf(v0.z); r.u[3] = f2bf(v0.w);
            r.u[4] = f2bf(v1.x); r.u[5] = f2bf(v1.y); r.u[6] = f2bf(v1.z); r.u[7] = f2bf(v1.w);
            breg[kt] = r.v;
        }
    }

    float win[I_DIM];
#pragma unroll
    for (int i = 0; i < I_DIM; ++i) win[i] = Win[n * I_DIM + i];

    unsigned short* hxg     = hx + (size_t)g * (2 * NB * H_DIM);
    unsigned*       gflags  = flags + g * 512;           // 64 slots, stride 8
    const unsigned* fl      = gflags + lane * 8;         // lane L polls slot L
    unsigned*       myflag  = gflags + (s * 8 + w) * 8;  // this wave's slot

    float hreg[4] = {0.f, 0.f, 0.f, 0.f};

#pragma unroll 1
    for (int t = 0; t < T_LEN; ++t) {
        // ---- off-path work: input drive dot-products + noise (cached loads) --
        float xd[4], nz[4];
#pragma unroll
        for (int r = 0; r < 4; ++r) {
            const float* xp = x + ((size_t)(b0 + kb * 4 + r) * T_LEN + t) * I_DIM;
            float sx = 0.f;
#pragma unroll
            for (int i = 0; i < I_DIM; ++i) sx += win[i] * xp[i];
            xd[r] = sx;
            nz[r] = noise[((size_t)(b0 + kb * 4 + r) * T_LEN + t) * H_DIM + n];
        }

        f32x4 acc0 = {0.f, 0.f, 0.f, 0.f}, acc1 = {0.f, 0.f, 0.f, 0.f};

        if (t > 0) {
            const unsigned tt = (unsigned)t;
            u64 rdy = 0;
            const u64* hq = (const u64*)(hxg + ((t - 1) & 1) * (NB * H_DIM))
                            + l15 * 256 + kb * 2;

#define WAITQ(q)                                                              \
            while (((rdy >> ((q) * 8)) & 0xFFull) != 0xFFull) {               \
                unsigned fv = AL(fl);                                         \
                rdy = __ballot(fv >= tt);                                     \
            }                                                                 \
            asm volatile("" ::: "memory");

#define ISSUE(A, q)                                                           \
            A[0] = AL(hq + ((q) * 4 + 0) * 8); A[1] = AL(hq + ((q) * 4 + 0) * 8 + 1); \
            A[2] = AL(hq + ((q) * 4 + 1) * 8); A[3] = AL(hq + ((q) * 4 + 1) * 8 + 1); \
            A[4] = AL(hq + ((q) * 4 + 2) * 8); A[5] = AL(hq + ((q) * 4 + 2) * 8 + 1); \
            A[6] = AL(hq + ((q) * 4 + 3) * 8); A[7] = AL(hq + ((q) * 4 + 3) * 8 + 1);

#define MF(A, q)                                                              \
            acc0 = __builtin_amdgcn_mfma_f32_16x16x32_bf16(mk(A[0], A[1]), breg[(q) * 4 + 0], acc0, 0, 0, 0); \
            acc1 = __builtin_amdgcn_mfma_f32_16x16x32_bf16(mk(A[2], A[3]), breg[(q) * 4 + 1], acc1, 0, 0, 0); \
            acc0 = __builtin_amdgcn_mfma_f32_16x16x32_bf16(mk(A[4], A[5]), breg[(q) * 4 + 2], acc0, 0, 0, 0); \
            acc1 = __builtin_amdgcn_mfma_f32_16x16x32_bf16(mk(A[6], A[7]), breg[(q) * 4 + 3], acc1, 0, 0, 0);

            u64 A0[8], A1[8];
            WAITQ(0) ISSUE(A0, 0)
            WAITQ(1) ISSUE(A1, 1) MF(A0, 0)
            WAITQ(2) ISSUE(A0, 2) MF(A1, 1)
            WAITQ(3) ISSUE(A1, 3) MF(A0, 2)
            WAITQ(4) ISSUE(A0, 4) MF(A1, 3)
            WAITQ(5) ISSUE(A1, 5) MF(A0, 4)
            WAITQ(6) ISSUE(A0, 6) MF(A1, 5)
            WAITQ(7) ISSUE(A1, 7) MF(A0, 6)
            MF(A1, 7)
#undef WAITQ
#undef ISSUE
#undef MF
        }

        // ---- epilogue: h_new = 0.9 h + 0.1 relu(acc + drive) ----
        const f32x4 acc = acc0 + acc1;
#pragma unroll
        for (int r = 0; r < 4; ++r) {
            const float pre = acc[r] + xd[r] + 0.1f * nz[r];
            hreg[r] = 0.9f * hreg[r] + 0.1f * fmaxf(pre, 0.f);
        }

        // ---- hiddens NT stores (drain in parallel with publish drain) ----
#pragma unroll
        for (int r = 0; r < 4; ++r)
            __builtin_nontemporal_store(
                hreg[r], &hiddens[((size_t)(b0 + kb * 4 + r) * T_LEN + t) * H_DIM + n]);

        // ---- publish h(t): packed col-pair u32, relaxed agent (L2-bypass) ---
        unsigned* hdst32 = (unsigned*)(hxg + (t & 1) * (NB * H_DIM));
#pragma unroll
        for (int r = 0; r < 4; ++r) {
            unsigned self  = f2bf(hreg[r]);
            unsigned other = __shfl_xor(self, 1, 64);
            if (!(l15 & 1))
                __hip_atomic_store(hdst32 + (kb * 4 + r) * (H_DIM / 2) + (n >> 1),
                                   self | (other << 16), __ATOMIC_RELAXED,
                                   __HIP_MEMORY_SCOPE_AGENT);
        }
        asm volatile("s_waitcnt vmcnt(0)" ::: "memory");  // publish acked at L3
        if (lane == 0)
            __hip_atomic_store(myflag, (unsigned)(t + 1), __ATOMIC_RELAXED,
                               __HIP_MEMORY_SCOPE_AGENT);
    }
}

// ---------------- output head: logits + softmax ----------------------------
__global__ __launch_bounds__(256)
void out_head(const float* __restrict__ hiddens, const float* __restrict__ Wout,
              float* __restrict__ outs)
{
    __shared__ float wlds[O_DIM][H_DIM];   // 32 KB
    const int tid = threadIdx.x;
    for (int j = tid; j < (O_DIM * H_DIM) / 4; j += 256)
        ((float4*)wlds)[j] = ((const float4*)Wout)[j];
    __syncthreads();

    const int wave = tid >> 6, lane = tid & 63;
#pragma unroll
    for (int rr = 0; rr < 2; ++rr) {
        const size_t row = (size_t)blockIdx.x * 8 + wave * 2 + rr;  // < 102400
        const float* hp = hiddens + row * H_DIM;

        float a0=0,a1=0,a2=0,a3=0,a4=0,a5=0,a6=0,a7=0;
#pragma unroll
        for (int j = 0; j < 4; ++j) {
            float4 hv = *(const float4*)(hp + lane * 4 + j * 256);
#define DOT(o, acc) { float4 wv = *(const float4*)&wlds[o][lane*4 + j*256]; \
                      acc += hv.x*wv.x + hv.y*wv.y + hv.z*wv.z + hv.w*wv.w; }
            DOT(0,a0) DOT(1,a1) DOT(2,a2) DOT(3,a3)
            DOT(4,a4) DOT(5,a5) DOT(6,a6) DOT(7,a7)
#undef DOT
        }
#pragma unroll
        for (int off = 32; off; off >>= 1) {
            a0 += __shfl_xor(a0, off, 64); a1 += __shfl_xor(a1, off, 64);
            a2 += __shfl_xor(a2, off, 64); a3 += __shfl_xor(a3, off, 64);
            a4 += __shfl_xor(a4, off, 64); a5 += __shfl_xor(a5, off, 64);
            a6 += __shfl_xor(a6, off, 64); a7 += __shfl_xor(a7, off, 64);
        }
        if (lane == 0) {
            float mx = fmaxf(fmaxf(fmaxf(a0,a1),fmaxf(a2,a3)),
                             fmaxf(fmaxf(a4,a5),fmaxf(a6,a7)));
            float e0=expf(a0-mx), e1=expf(a1-mx), e2=expf(a2-mx), e3=expf(a3-mx);
            float e4=expf(a4-mx), e5=expf(a5-mx), e6=expf(a6-mx), e7=expf(a7-mx);
            float inv = 1.f / (e0+e1+e2+e3+e4+e5+e6+e7);
            float* op = outs + row * O_DIM;
            op[0]=e0*inv; op[1]=e1*inv; op[2]=e2*inv; op[3]=e3*inv;
            op[4]=e4*inv; op[5]=e5*inv; op[6]=e6*inv; op[7]=e7*inv;
        }
    }
}

extern "C" void kernel_launch(void* const* d_in, const int* in_sizes, int n_in,
                              void* d_out, int out_size, void* d_ws, size_t ws_size,
                              hipStream_t stream) {
    const float* x     = (const float*)d_in[0];   // [128][800][9]
    const float* noise = (const float*)d_in[1];   // [128][800][1024]
    const float* Win   = (const float*)d_in[2];   // [1024][9]
    const float* Wrec  = (const float*)d_in[3];   // [1024][1024]
    const float* Wout  = (const float*)d_in[4];   // [8][1024]

    float* hiddens = (float*)d_out;                                // 104857600 f32
    float* outs    = hiddens + (size_t)B_TOT * T_LEN * H_DIM;      // 819200 f32

    // ws layout: [0, 16KB) per-wave flags (memset each launch -> deterministic
    // replay), [16KB, 16KB+512KB) bf16 h exchange double-buffer.
    unsigned*       flags = (unsigned*)d_ws;
    unsigned short* hx    = (unsigned short*)((char*)d_ws + 16384);

    hipMemsetAsync(d_ws, 0, 16384, stream);
    rnn_scan<<<GROUPS * NSLC, 512, 0, stream>>>(x, noise, Win, Wrec, hx, flags, hiddens);
    out_head<<<(B_TOT * T_LEN) / 8, 256, 0, stream>>>(hiddens, Wout, outs);
}

// Round 6
// 6834.634 us; speedup vs baseline: 2.1140x; 2.1140x over previous
//
#include <hip/hip_runtime.h>

#define B_TOT 128
#define T_LEN 800
#define I_DIM 9
#define H_DIM 1024
#define O_DIM 8
#define NB    16            // batches per group (one M=16 MFMA tile)
#define NSLC  8             // blocks per group (N-split)
#define NCOL  128           // output columns per block (8 waves x 16)
#define GROUPS (B_TOT / NB) // 8

typedef float f32x4 __attribute__((ext_vector_type(4)));
typedef short s16x8 __attribute__((ext_vector_type(8)));
typedef unsigned long long u64;

#define TAGM 0x0000800000008000ull   // bit15 of each u32 (sign of low bf16; h>=0)

__device__ __forceinline__ unsigned short f2bf(float f) {
    unsigned u = __float_as_uint(f);
    u += 0x7fffu + ((u >> 16) & 1u);   // round-to-nearest-even
    return (unsigned short)(u >> 16);
}

#define AL(p) __hip_atomic_load((p), __ATOMIC_RELAXED, __HIP_MEMORY_SCOPE_AGENT)
#define AS(p, v) __hip_atomic_store((p), (v), __ATOMIC_RELAXED, __HIP_MEMORY_SCOPE_AGENT)

// swizzled LDS map: logical 16B slot s in row r -> physical slot.
// bijective per row; gather-write (same row, s stride 4) and MFMA-read
// (same s, rows vary) both spread across all 8 bank groups -> conflict-free.
__device__ __forceinline__ int swz(int s, int r) {
    return s ^ ((s >> 3) & 7) ^ (r & 7);
}

// -------- recurrent scan: 64 blocks (8 groups x 8 N-slices) -----------------
// r4 skeleton (coarse step, cooperative gather, LDS GEMM) with self-signaling
// TAGGED data: step tag lives in bit15 of every published u32 (h >= 0 so the
// bf16 sign bit is free). No flags, no vmcnt drain, no separate poll hop --
// consumers gather data words and accept when all tags match. One barrier
// per step (LDS tile + xs double-buffered).
__global__ __launch_bounds__(512, 2)
void rnn_scan(const float* __restrict__ x,        // [B][T][9]
              const float* __restrict__ noise,    // [B][T][H]
              const float* __restrict__ Win,      // [H][9]
              const float* __restrict__ Wrec,     // [H][H] f32, row n = out col
              unsigned short* __restrict__ hx,    // [G][2][NB][H] bf16+tag
              float* __restrict__ hiddens)        // [B][T][H] f32 out
{
    __shared__ char  hlds[2][NB * 2048];   // 64 KB double-buffered h tile
    __shared__ float xs[2][NB][I_DIM];

    const int tid  = threadIdx.x;
    const int lane = tid & 63;
    const int w    = tid >> 6;          // wave 0..7, owns 16 columns
    const int g    = blockIdx.x & 7;    // group (same-XCD affinity heuristic)
    const int s    = blockIdx.x >> 3;   // N-slice 0..7
    const int b0   = g * NB;
    const int l15  = lane & 15;
    const int kb   = lane >> 4;
    const int n    = s * NCOL + w * 16 + l15;   // this lane's output column

    // ---- prologue: Wrec row n -> bf16 B-fragments in registers (64 VGPR) ---
    s16x8 breg[32];
    {
        const float* wrow = Wrec + (size_t)n * H_DIM + kb * 8;
#pragma unroll
        for (int kt = 0; kt < 32; ++kt) {
            float4 v0 = *(const float4*)(wrow + kt * 32);
            float4 v1 = *(const float4*)(wrow + kt * 32 + 4);
            union { s16x8 v; unsigned short u[8]; } r;
            r.u[0] = f2bf(v0.x); r.u[1] = f2bf(v0.y); r.u[2] = f2bf(v0.z); r.u[3] = f2bf(v0.w);
            r.u[4] = f2bf(v1.x); r.u[5] = f2bf(v1.y); r.u[6] = f2bf(v1.z); r.u[7] = f2bf(v1.w);
            breg[kt] = r.v;
        }
    }

    float win[I_DIM];
#pragma unroll
    for (int i = 0; i < I_DIM; ++i) win[i] = Win[n * I_DIM + i];

    unsigned short* hxg = hx + (size_t)g * (2 * NB * H_DIM);

    // cooperative-gather geometry: wave w pulls rows {2w, 2w+1}, 64B per lane
    const int grow = 2 * w + (lane >> 5);     // 0..15
    const int gl   = lane & 31;               // 16B slot base = gl*4

    float hreg[4] = {0.f, 0.f, 0.f, 0.f};

#pragma unroll 1
    for (int t = 0; t < T_LEN; ++t) {
        const int pb = t & 1;          // LDS buffer / hx publish buffer parity

        // ---- (1) issue tagged gather ASAP (h(t-1) lives in hx buf[(t-1)&1]) --
        u64 v[8];
        const u64* src = (const u64*)(hxg + ((t - 1) & 1) * (NB * H_DIM))
                         + grow * 256 + gl * 8;
        if (t > 0) {
#pragma unroll
            for (int j = 0; j < 8; ++j) v[j] = AL(src + j);
        }

        // ---- (2) off-path: stage x(t), prefetch noise(t) ----
        if (tid < NB * I_DIM) {
            int b = tid / I_DIM, i = tid - b * I_DIM;
            xs[pb][b][i] = x[((size_t)(b0 + b) * T_LEN + t) * I_DIM + i];
        }
        float nz[4];
#pragma unroll
        for (int r = 0; r < 4; ++r)
            nz[r] = noise[((size_t)(b0 + kb * 4 + r) * T_LEN + t) * H_DIM + n];

        if (t > 0) {
            // ---- (3) accept when every word carries this step's tag ----
            const u64 exp = (((t - 1) >> 1) & 1) ? TAGM : 0ull;
            for (;;) {
                u64 bad = 0;
#pragma unroll
                for (int j = 0; j < 8; ++j) bad |= (v[j] ^ exp) & TAGM;
                if (__all(bad == 0)) break;
#pragma unroll
                for (int j = 0; j < 8; ++j) v[j] = AL(src + j);
            }
            // ---- (4) untag + swizzled LDS write (conflict-free) ----
            char* drow = hlds[pb] + grow * 2048;
#pragma unroll
            for (int j2 = 0; j2 < 4; ++j2) {
                ulonglong2 q;
                q.x = v[2 * j2] & ~TAGM;
                q.y = v[2 * j2 + 1] & ~TAGM;
                *(ulonglong2*)(drow + swz(gl * 4 + j2, grow) * 16) = q;
            }
        }
        __syncthreads();   // tile + xs ready (single barrier per step)

        // ---- (5) drive: xd[r] = Win[n] . x[b][t] ----
        float xd[4];
#pragma unroll
        for (int r = 0; r < 4; ++r) {
            float sx = 0.f;
#pragma unroll
            for (int i = 0; i < I_DIM; ++i) sx += win[i] * xs[pb][kb * 4 + r][i];
            xd[r] = sx;
        }

        // ---- (6) GEMM from LDS: acc = sum_k h(t-1)[b][k] * Wrec[n][k] ----
        f32x4 acc0 = {0.f, 0.f, 0.f, 0.f}, acc1 = {0.f, 0.f, 0.f, 0.f};
        if (t > 0) {
            const char* rrow = hlds[pb] + l15 * 2048;
#pragma unroll
            for (int kt = 0; kt < 32; kt += 2) {
                s16x8 a0 = *(const s16x8*)(rrow + swz(kt * 4 + kb, l15) * 16);
                acc0 = __builtin_amdgcn_mfma_f32_16x16x32_bf16(a0, breg[kt], acc0, 0, 0, 0);
                s16x8 a1 = *(const s16x8*)(rrow + swz(kt * 4 + 4 + kb, l15) * 16);
                acc1 = __builtin_amdgcn_mfma_f32_16x16x32_bf16(a1, breg[kt + 1], acc1, 0, 0, 0);
            }
        }
        const f32x4 acc = acc0 + acc1;

        // ---- (7) epilogue: h_new = 0.9 h + 0.1 relu(acc + drive) ----
#pragma unroll
        for (int r = 0; r < 4; ++r) {
            const float pre = acc[r] + xd[r] + 0.1f * nz[r];
            hreg[r] = 0.9f * hreg[r] + 0.1f * fmaxf(pre, 0.f);
        }

        // ---- (8) publish h(t) FIRST (tagged, self-signaling), then hiddens --
        const unsigned tagbit = (unsigned)((t >> 1) & 1) << 15;
        unsigned* hdst32 = (unsigned*)(hxg + pb * (NB * H_DIM));
#pragma unroll
        for (int r = 0; r < 4; ++r) {
            unsigned self  = f2bf(hreg[r]);
            unsigned other = __shfl_xor(self, 1, 64);
            if (!(l15 & 1))
                AS(hdst32 + (kb * 4 + r) * (H_DIM / 2) + (n >> 1),
                   self | (other << 16) | tagbit);
        }
#pragma unroll
        for (int r = 0; r < 4; ++r)
            __builtin_nontemporal_store(
                hreg[r], &hiddens[((size_t)(b0 + kb * 4 + r) * T_LEN + t) * H_DIM + n]);
    }
}

// ---------------- output head: logits + softmax ----------------------------
__global__ __launch_bounds__(256)
void out_head(const float* __restrict__ hiddens, const float* __restrict__ Wout,
              float* __restrict__ outs)
{
    __shared__ float wlds[O_DIM][H_DIM];   // 32 KB
    const int tid = threadIdx.x;
    for (int j = tid; j < (O_DIM * H_DIM) / 4; j += 256)
        ((float4*)wlds)[j] = ((const float4*)Wout)[j];
    __syncthreads();

    const int wave = tid >> 6, lane = tid & 63;
#pragma unroll
    for (int rr = 0; rr < 2; ++rr) {
        const size_t row = (size_t)blockIdx.x * 8 + wave * 2 + rr;  // < 102400
        const float* hp = hiddens + row * H_DIM;

        float a0=0,a1=0,a2=0,a3=0,a4=0,a5=0,a6=0,a7=0;
#pragma unroll
        for (int j = 0; j < 4; ++j) {
            float4 hv = *(const float4*)(hp + lane * 4 + j * 256);
#define DOT(o, acc) { float4 wv = *(const float4*)&wlds[o][lane*4 + j*256]; \
                      acc += hv.x*wv.x + hv.y*wv.y + hv.z*wv.z + hv.w*wv.w; }
            DOT(0,a0) DOT(1,a1) DOT(2,a2) DOT(3,a3)
            DOT(4,a4) DOT(5,a5) DOT(6,a6) DOT(7,a7)
#undef DOT
        }
#pragma unroll
        for (int off = 32; off; off >>= 1) {
            a0 += __shfl_xor(a0, off, 64); a1 += __shfl_xor(a1, off, 64);
            a2 += __shfl_xor(a2, off, 64); a3 += __shfl_xor(a3, off, 64);
            a4 += __shfl_xor(a4, off, 64); a5 += __shfl_xor(a5, off, 64);
            a6 += __shfl_xor(a6, off, 64); a7 += __shfl_xor(a7, off, 64);
        }
        if (lane == 0) {
            float mx = fmaxf(fmaxf(fmaxf(a0,a1),fmaxf(a2,a3)),
                             fmaxf(fmaxf(a4,a5),fmaxf(a6,a7)));
            float e0=expf(a0-mx), e1=expf(a1-mx), e2=expf(a2-mx), e3=expf(a3-mx);
            float e4=expf(a4-mx), e5=expf(a5-mx), e6=expf(a6-mx), e7=expf(a7-mx);
            float inv = 1.f / (e0+e1+e2+e3+e4+e5+e6+e7);
            float* op = outs + row * O_DIM;
            op[0]=e0*inv; op[1]=e1*inv; op[2]=e2*inv; op[3]=e3*inv;
            op[4]=e4*inv; op[5]=e5*inv; op[6]=e6*inv; op[7]=e7*inv;
        }
    }
}

extern "C" void kernel_launch(void* const* d_in, const int* in_sizes, int n_in,
                              void* d_out, int out_size, void* d_ws, size_t ws_size,
                              hipStream_t stream) {
    const float* x     = (const float*)d_in[0];   // [128][800][9]
    const float* noise = (const float*)d_in[1];   // [128][800][1024]
    const float* Win   = (const float*)d_in[2];   // [1024][9]
    const float* Wrec  = (const float*)d_in[3];   // [1024][1024]
    const float* Wout  = (const float*)d_in[4];   // [8][1024]

    float* hiddens = (float*)d_out;                                // 104857600 f32
    float* outs    = hiddens + (size_t)B_TOT * T_LEN * H_DIM;      // 819200 f32

    // ws: [0, 512KB) tagged bf16 h exchange double-buffer. 0xFF fill = tag1
    // in every word -> t=1 consumers (expect tag0) can never accept residue;
    // later steps are protected by the in-run tag alternation.
    unsigned short* hx = (unsigned short*)d_ws;

    hipMemsetAsync(d_ws, 0xFF, (size_t)GROUPS * 2 * NB * H_DIM * 2, stream);
    rnn_scan<<<GROUPS * NSLC, 512, 0, stream>>>(x, noise, Win, Wrec, hx, hiddens);
    out_head<<<(B_TOT * T_LEN) / 8, 256, 0, stream>>>(hiddens, Wout, outs);
}

// Round 7
// 4888.460 us; speedup vs baseline: 2.9556x; 1.3981x over previous
//
#include <hip/hip_runtime.h>

#define B_TOT 128
#define T_LEN 800
#define I_DIM 9
#define H_DIM 1024
#define O_DIM 8
#define NB    16            // batches per group (one M=16 MFMA tile)
#define NSLC  8             // blocks per group (N-split)
#define NCOL  128           // output columns per block (8 waves x 16)
#define GROUPS (B_TOT / NB) // 8

typedef float f32x4 __attribute__((ext_vector_type(4)));
typedef short s16x8 __attribute__((ext_vector_type(8)));
typedef unsigned long long u64;

__device__ __forceinline__ unsigned short f2bf(float f) {
    unsigned u = __float_as_uint(f);
    u += 0x7fffu + ((u >> 16) & 1u);   // round-to-nearest-even
    return (unsigned short)(u >> 16);
}

#define AL(p) __hip_atomic_load((p), __ATOMIC_RELAXED, __HIP_MEMORY_SCOPE_AGENT)
#define AS(p, v) __hip_atomic_store((p), (v), __ATOMIC_RELAXED, __HIP_MEMORY_SCOPE_AGENT)

// Conflict-free LDS map: logical 16B slot s of row r -> physical slot.
// Derivation: bank-group = phys & 7. Gather-write slots s = gl + 32j
// (32 lanes, row fixed): low3 = (gl&7)^((gl>>3 + 4j)&7) -> each group 4x. ok
// MFMA-read slots s = 4kt+kb (16 rows x 4 kb): low3 = kb^C^(r&7) -> each
// group 8x over 64 lanes. ok  Bijective per row (XOR of low 3 bits).
__device__ __forceinline__ int swz(int s, int r) {
    return s ^ ((s >> 3) & 7) ^ (r & 7);
}

// -------- recurrent scan: 64 blocks (8 groups x 8 N-slices) -----------------
// r4 skeleton, sync-lean: per-producer-WAVE flags (64/group). Producer:
// publish sc1 -> vmcnt(0) -> own-flag store (no block sync). Consumer: every
// wave independently ballot-polls all 64 flags in one round (64 lanes x one
// 4B load), gathers its 2 rows contiguously, swizzled LDS write, ONE
// __syncthreads, GEMM from LDS. Flags are monotone -> no deadlock; flag>=t
// ordering makes the double-buffer WAR-safe.
__global__ __launch_bounds__(512, 1)
void rnn_scan(const float* __restrict__ x,        // [B][T][9]
              const float* __restrict__ noise,    // [B][T][H]
              const float* __restrict__ Win,      // [H][9]
              const float* __restrict__ Wrec,     // [H][H] f32, row n = out col
              unsigned short* __restrict__ hx,    // [G][2][NB][H] bf16 exchange
              unsigned* __restrict__ flags,       // [G][64] per-wave flags
              float* __restrict__ hiddens)        // [B][T][H] f32 out
{
    __shared__ __align__(16) char hlds[2][NB * 2048];   // 64 KB dbuf h tile
    __shared__ float xs[2][NB][I_DIM];

    const int tid  = threadIdx.x;
    const int lane = tid & 63;
    const int w    = tid >> 6;          // wave 0..7, owns 16 columns
    const int g    = blockIdx.x & 7;    // group (same-XCD affinity heuristic)
    const int s    = blockIdx.x >> 3;   // N-slice 0..7
    const int b0   = g * NB;
    const int l15  = lane & 15;
    const int kb   = lane >> 4;
    const int n    = s * NCOL + w * 16 + l15;   // this lane's output column

    // ---- prologue: Wrec row n -> bf16 B-fragments in registers ----
    s16x8 breg[32];
    {
        const float* wrow = Wrec + (size_t)n * H_DIM + kb * 8;
#pragma unroll
        for (int kt = 0; kt < 32; ++kt) {
            float4 v0 = *(const float4*)(wrow + kt * 32);
            float4 v1 = *(const float4*)(wrow + kt * 32 + 4);
            union { s16x8 v; unsigned short u[8]; } r;
            r.u[0] = f2bf(v0.x); r.u[1] = f2bf(v0.y); r.u[2] = f2bf(v0.z); r.u[3] = f2bf(v0.w);
            r.u[4] = f2bf(v1.x); r.u[5] = f2bf(v1.y); r.u[6] = f2bf(v1.z); r.u[7] = f2bf(v1.w);
            breg[kt] = r.v;
        }
    }

    float win[I_DIM];
#pragma unroll
    for (int i = 0; i < I_DIM; ++i) win[i] = Win[n * I_DIM + i];

    unsigned short* hxg    = hx + (size_t)g * (2 * NB * H_DIM);
    unsigned*       gflags = flags + g * 64;          // 64 producer-wave flags
    unsigned*       myflag = gflags + (s * 8 + w);

    // gather geometry: wave w pulls rows {2w, 2w+1}; lane gl reads 4x16B at
    // byte gl*16 + j*512 (each instruction covers 512B contiguous).
    const int grow = 2 * w + (lane >> 5);     // 0..15
    const int gl   = lane & 31;

    float hreg[4] = {0.f, 0.f, 0.f, 0.f};

#pragma unroll 1
    for (int t = 0; t < T_LEN; ++t) {
        const int pb = t & 1;

        // ---- off-path: stage x(t) to LDS buf, prefetch noise(t) ----
        if (tid < NB * I_DIM) {
            int b = tid / I_DIM, i = tid - b * I_DIM;
            xs[pb][b][i] = x[((size_t)(b0 + b) * T_LEN + t) * I_DIM + i];
        }
        float nz[4];
#pragma unroll
        for (int r = 0; r < 4; ++r)
            nz[r] = noise[((size_t)(b0 + kb * 4 + r) * T_LEN + t) * H_DIM + n];

        if (t > 0) {
            // ---- every wave ballot-polls all 64 producer flags (1 round) ---
            const unsigned tt = (unsigned)t;
            unsigned fv;
            do { fv = AL(gflags + lane); } while (!__all(fv >= tt));
            asm volatile("" ::: "memory");   // no gather hoisting above poll

            // ---- gather 2 rows of h(t-1), contiguous 16B/lane chunks ----
            const u64* srow = (const u64*)(hxg + ((t - 1) & 1) * (NB * H_DIM))
                              + grow * 256 + gl * 2;
            u64 v[8];
#pragma unroll
            for (int jj = 0; jj < 4; ++jj) {
                v[2 * jj]     = AL(srow + jj * 64);
                v[2 * jj + 1] = AL(srow + jj * 64 + 1);
            }
            // ---- swizzled LDS write (conflict-free, 16B) ----
            char* drow = hlds[pb] + grow * 2048;
#pragma unroll
            for (int jj = 0; jj < 4; ++jj) {
                ulonglong2 q; q.x = v[2 * jj]; q.y = v[2 * jj + 1];
                *(ulonglong2*)(drow + swz(gl + jj * 32, grow) * 16) = q;
            }
        }
        __syncthreads();   // single barrier: tile + xs ready

        // ---- drive: xd[r] = Win[n] . x[b][t] ----
        float xd[4];
#pragma unroll
        for (int r = 0; r < 4; ++r) {
            float sx = 0.f;
#pragma unroll
            for (int i = 0; i < I_DIM; ++i) sx += win[i] * xs[pb][kb * 4 + r][i];
            xd[r] = sx;
        }

        // ---- GEMM from LDS: acc = sum_k h(t-1)[b][k] * Wrec[n][k] ----
        f32x4 acc0 = {0.f, 0.f, 0.f, 0.f}, acc1 = {0.f, 0.f, 0.f, 0.f};
        if (t > 0) {
            const char* rrow = hlds[pb] + l15 * 2048;
#pragma unroll
            for (int kt = 0; kt < 32; kt += 2) {
                s16x8 a0 = *(const s16x8*)(rrow + swz(4 * kt + kb, l15) * 16);
                acc0 = __builtin_amdgcn_mfma_f32_16x16x32_bf16(a0, breg[kt], acc0, 0, 0, 0);
                s16x8 a1 = *(const s16x8*)(rrow + swz(4 * kt + 4 + kb, l15) * 16);
                acc1 = __builtin_amdgcn_mfma_f32_16x16x32_bf16(a1, breg[kt + 1], acc1, 0, 0, 0);
            }
        }
        const f32x4 acc = acc0 + acc1;

        // ---- epilogue: h_new = 0.9 h + 0.1 relu(acc + drive) ----
#pragma unroll
        for (int r = 0; r < 4; ++r) {
            const float pre = acc[r] + xd[r] + 0.1f * nz[r];
            hreg[r] = 0.9f * hreg[r] + 0.1f * fmaxf(pre, 0.f);
        }

        // ---- publish h(t) -> vmcnt(0) -> own flag (no block sync) ----
        unsigned* hdst32 = (unsigned*)(hxg + pb * (NB * H_DIM));
#pragma unroll
        for (int r = 0; r < 4; ++r) {
            unsigned self  = f2bf(hreg[r]);
            unsigned other = __shfl_xor(self, 1, 64);
            if (!(l15 & 1))
                AS(hdst32 + (kb * 4 + r) * (H_DIM / 2) + (n >> 1),
                   self | (other << 16));
        }
        asm volatile("s_waitcnt vmcnt(0)" ::: "memory");  // publish acked at L3
        if (lane == 0)
            AS(myflag, (unsigned)(t + 1));

        // ---- hiddens NT stores off the critical path ----
#pragma unroll
        for (int r = 0; r < 4; ++r)
            __builtin_nontemporal_store(
                hreg[r], &hiddens[((size_t)(b0 + kb * 4 + r) * T_LEN + t) * H_DIM + n]);
    }
}

// ---------------- output head: logits + softmax ----------------------------
__global__ __launch_bounds__(256)
void out_head(const float* __restrict__ hiddens, const float* __restrict__ Wout,
              float* __restrict__ outs)
{
    __shared__ float wlds[O_DIM][H_DIM];   // 32 KB
    const int tid = threadIdx.x;
    for (int j = tid; j < (O_DIM * H_DIM) / 4; j += 256)
        ((float4*)wlds)[j] = ((const float4*)Wout)[j];
    __syncthreads();

    const int wave = tid >> 6, lane = tid & 63;
#pragma unroll
    for (int rr = 0; rr < 2; ++rr) {
        const size_t row = (size_t)blockIdx.x * 8 + wave * 2 + rr;  // < 102400
        const float* hp = hiddens + row * H_DIM;

        float a0=0,a1=0,a2=0,a3=0,a4=0,a5=0,a6=0,a7=0;
#pragma unroll
        for (int j = 0; j < 4; ++j) {
            float4 hv = *(const float4*)(hp + lane * 4 + j * 256);
#define DOT(o, acc) { float4 wv = *(const float4*)&wlds[o][lane*4 + j*256]; \
                      acc += hv.x*wv.x + hv.y*wv.y + hv.z*wv.z + hv.w*wv.w; }
            DOT(0,a0) DOT(1,a1) DOT(2,a2) DOT(3,a3)
            DOT(4,a4) DOT(5,a5) DOT(6,a6) DOT(7,a7)
#undef DOT
        }
#pragma unroll
        for (int off = 32; off; off >>= 1) {
            a0 += __shfl_xor(a0, off, 64); a1 += __shfl_xor(a1, off, 64);
            a2 += __shfl_xor(a2, off, 64); a3 += __shfl_xor(a3, off, 64);
            a4 += __shfl_xor(a4, off, 64); a5 += __shfl_xor(a5, off, 64);
            a6 += __shfl_xor(a6, off, 64); a7 += __shfl_xor(a7, off, 64);
        }
        if (lane == 0) {
            float mx = fmaxf(fmaxf(fmaxf(a0,a1),fmaxf(a2,a3)),
                             fmaxf(fmaxf(a4,a5),fmaxf(a6,a7)));
            float e0=expf(a0-mx), e1=expf(a1-mx), e2=expf(a2-mx), e3=expf(a3-mx);
            float e4=expf(a4-mx), e5=expf(a5-mx), e6=expf(a6-mx), e7=expf(a7-mx);
            float inv = 1.f / (e0+e1+e2+e3+e4+e5+e6+e7);
            float* op = outs + row * O_DIM;
            op[0]=e0*inv; op[1]=e1*inv; op[2]=e2*inv; op[3]=e3*inv;
            op[4]=e4*inv; op[5]=e5*inv; op[6]=e6*inv; op[7]=e7*inv;
        }
    }
}

extern "C" void kernel_launch(void* const* d_in, const int* in_sizes, int n_in,
                              void* d_out, int out_size, void* d_ws, size_t ws_size,
                              hipStream_t stream) {
    const float* x     = (const float*)d_in[0];   // [128][800][9]
    const float* noise = (const float*)d_in[1];   // [128][800][1024]
    const float* Win   = (const float*)d_in[2];   // [1024][9]
    const float* Wrec  = (const float*)d_in[3];   // [1024][1024]
    const float* Wout  = (const float*)d_in[4];   // [8][1024]

    float* hiddens = (float*)d_out;                                // 104857600 f32
    float* outs    = hiddens + (size_t)B_TOT * T_LEN * H_DIM;      // 819200 f32

    // ws layout: [0, 4KB) per-wave flags (memset each launch -> deterministic
    // replay), [4KB, 4KB+512KB) bf16 h exchange double-buffer.
    unsigned*       flags = (unsigned*)d_ws;
    unsigned short* hx    = (unsigned short*)((char*)d_ws + 4096);

    hipMemsetAsync(d_ws, 0, 4096, stream);
    rnn_scan<<<GROUPS * NSLC, 512, 0, stream>>>(x, noise, Win, Wrec, hx, flags, hiddens);
    out_head<<<(B_TOT * T_LEN) / 8, 256, 0, stream>>>(hiddens, Wout, outs);
}

// Round 8
// 3475.310 us; speedup vs baseline: 4.1575x; 1.4066x over previous
//
#include <hip/hip_runtime.h>

#define B_TOT 128
#define T_LEN 800
#define I_DIM 9
#define H_DIM 1024
#define O_DIM 8
#define NB    16            // batches per group (one M=16 MFMA tile)
#define NSLC  8             // blocks per group (N-split); stripe s <-> producer s
#define NCOL  128           // output columns per block (8 waves x 16)
#define GROUPS (B_TOT / NB) // 8

typedef float f32x4 __attribute__((ext_vector_type(4)));
typedef short s16x8 __attribute__((ext_vector_type(8)));
typedef unsigned long long u64;

#define TAGM 0x0000800000008000ull   // bit15 of each u32 (sign of low bf16; h>=0)

__device__ __forceinline__ unsigned short f2bf(float f) {
    unsigned u = __float_as_uint(f);
    u += 0x7fffu + ((u >> 16) & 1u);   // round-to-nearest-even
    return (unsigned short)(u >> 16);
}

#define AL(p) __hip_atomic_load((p), __ATOMIC_RELAXED, __HIP_MEMORY_SCOPE_AGENT)
#define AS(p, v) __hip_atomic_store((p), (v), __ATOMIC_RELAXED, __HIP_MEMORY_SCOPE_AGENT)

// Conflict-minimal LDS map (r7-proven): logical 16B slot s of row r -> phys.
__device__ __forceinline__ int swz(int s, int r) {
    return s ^ ((s >> 3) & 7) ^ (r & 7);
}

// -------- recurrent scan: 64 blocks (8 groups x 8 N-slices) -----------------
// Signal IS data: h published as bf16 pairs with step-parity tag in bit15.
// Consumer wave w gathers ONLY producer w's 4KB stripe, retrying stale 8B
// pairs individually; hands it to the block via an LDS release word (strd).
// GEMM consumes stripes 0..7 with LDS acquire spins -> compute overlaps
// straggler stripes. No flags, no producer drain, one __syncthreads/step.
__global__ __launch_bounds__(512, 1)
void rnn_scan(const float* __restrict__ x,        // [B][T][9]
              const float* __restrict__ noise,    // [B][T][H]
              const float* __restrict__ Win,      // [H][9]
              const float* __restrict__ Wrec,     // [H][H] f32, row n = out col
              unsigned short* __restrict__ hx,    // [G][2][NB][H] bf16+tag
              float* __restrict__ hiddens)        // [B][T][H] f32 out
{
    __shared__ __align__(16) char hlds[2][NB * 2048];   // 64 KB dbuf h tile
    __shared__ float xs[2][NB][I_DIM];
    __shared__ int strd[2][NSLC];                       // stripe-ready (step #)

    const int tid  = threadIdx.x;
    const int lane = tid & 63;
    const int w    = tid >> 6;          // wave 0..7: owns 16 cols + stripe w
    const int g    = blockIdx.x & 7;    // group
    const int s    = blockIdx.x >> 3;   // N-slice 0..7
    const int b0   = g * NB;
    const int l15  = lane & 15;
    const int kb   = lane >> 4;
    const int n    = s * NCOL + w * 16 + l15;   // this lane's output column

    // ---- prologue: Wrec row n -> bf16 B-fragments in registers ----
    s16x8 breg[32];
    {
        const float* wrow = Wrec + (size_t)n * H_DIM + kb * 8;
#pragma unroll
        for (int kt = 0; kt < 32; ++kt) {
            float4 v0 = *(const float4*)(wrow + kt * 32);
            float4 v1 = *(const float4*)(wrow + kt * 32 + 4);
            union { s16x8 v; unsigned short u[8]; } r;
            r.u[0] = f2bf(v0.x); r.u[1] = f2bf(v0.y); r.u[2] = f2bf(v0.z); r.u[3] = f2bf(v0.w);
            r.u[4] = f2bf(v1.x); r.u[5] = f2bf(v1.y); r.u[6] = f2bf(v1.z); r.u[7] = f2bf(v1.w);
            breg[kt] = r.v;
        }
    }

    float win[I_DIM];
#pragma unroll
    for (int i = 0; i < I_DIM; ++i) win[i] = Win[n * I_DIM + i];

    unsigned short* hxg = hx + (size_t)g * (2 * NB * H_DIM);

    // stripe-gather geometry: lane -> (row grow, 64B quarter gq) of stripe w
    const int grow = lane >> 2;        // 0..15 (batch row)
    const int gq   = lane & 3;         // 16B sub-slot within each 64B chunk

    if (tid < 2 * NSLC) ((int*)strd)[tid] = 0;
    float hreg[4] = {0.f, 0.f, 0.f, 0.f};
    __syncthreads();

#pragma unroll 1
    for (int t = 0; t < T_LEN; ++t) {
        const int pb = t & 1;

        // ---- stage x(t), prefetch noise(t) (overlaps everything below) ----
        if (tid < NB * I_DIM) {
            int b = tid / I_DIM, i = tid - b * I_DIM;
            xs[pb][b][i] = x[((size_t)(b0 + b) * T_LEN + t) * I_DIM + i];
        }
        float nz[4];
#pragma unroll
        for (int r = 0; r < 4; ++r)
            nz[r] = noise[((size_t)(b0 + kb * 4 + r) * T_LEN + t) * H_DIM + n];

        f32x4 acc0 = {0.f, 0.f, 0.f, 0.f}, acc1 = {0.f, 0.f, 0.f, 0.f};

        if (t == 0) {
            __syncthreads();           // xs visible for the t=0 drive
        } else {
            // ---- gather stripe w of h(t-1), tag-validated, per-pair retry --
            const u64 exp = (((t - 1) >> 1) & 1) ? TAGM : 0ull;
            const u64* sp = (const u64*)(hxg + ((t - 1) & 1) * (NB * H_DIM))
                            + grow * 256 + w * 32 + gq * 2;
            u64 v[8];
#pragma unroll
            for (int j = 0; j < 4; ++j) {
                v[2 * j]     = AL(sp + j * 8);
                v[2 * j + 1] = AL(sp + j * 8 + 1);
            }
            for (;;) {
                u64 bad = 0;
#pragma unroll
                for (int j = 0; j < 8; ++j) bad |= (v[j] ^ exp) & TAGM;
                if (__all(bad == 0)) break;
#pragma unroll
                for (int j = 0; j < 4; ++j) {            // reload stale pairs only
                    if ((((v[2 * j] ^ exp) | (v[2 * j + 1] ^ exp)) & TAGM) != 0) {
                        v[2 * j]     = AL(sp + j * 8);
                        v[2 * j + 1] = AL(sp + j * 8 + 1);
                    }
                }
            }
            // ---- untag + swizzled LDS write; release stripe to the block ---
            char* drow = hlds[pb] + grow * 2048;
#pragma unroll
            for (int j = 0; j < 4; ++j) {
                ulonglong2 q2;
                q2.x = v[2 * j] & ~TAGM;
                q2.y = v[2 * j + 1] & ~TAGM;
                *(ulonglong2*)(drow + swz(w * 16 + gq + j * 4, grow) * 16) = q2;
            }
            if (lane == 0)
                __hip_atomic_store(&strd[pb][w], t, __ATOMIC_RELEASE,
                                   __HIP_MEMORY_SCOPE_WORKGROUP);

            // ---- GEMM: consume stripes 0..7, spinning only when needed ----
            const char* rrow = hlds[pb] + l15 * 2048;
#pragma unroll
            for (int j = 0; j < 8; ++j) {
                if (j != w) {
                    while (__hip_atomic_load(&strd[pb][j], __ATOMIC_ACQUIRE,
                                             __HIP_MEMORY_SCOPE_WORKGROUP) < t) {}
                }
#pragma unroll
                for (int kk = 0; kk < 4; kk += 2) {
                    const int kt = 4 * j + kk;   // compile-time breg index
                    s16x8 a0 = *(const s16x8*)(rrow + swz(4 * kt + kb, l15) * 16);
                    acc0 = __builtin_amdgcn_mfma_f32_16x16x32_bf16(a0, breg[kt], acc0, 0, 0, 0);
                    s16x8 a1 = *(const s16x8*)(rrow + swz(4 * kt + 4 + kb, l15) * 16);
                    acc1 = __builtin_amdgcn_mfma_f32_16x16x32_bf16(a1, breg[kt + 1], acc1, 0, 0, 0);
                }
            }
        }
        const f32x4 acc = acc0 + acc1;

        // ---- drive (xs guaranteed by strd chain / t=0 barrier) ----
        float xd[4];
#pragma unroll
        for (int r = 0; r < 4; ++r) {
            float sx = 0.f;
#pragma unroll
            for (int i = 0; i < I_DIM; ++i) sx += win[i] * xs[pb][kb * 4 + r][i];
            xd[r] = sx;
        }

        // ---- epilogue: h_new = 0.9 h + 0.1 relu(acc + drive) ----
#pragma unroll
        for (int r = 0; r < 4; ++r) {
            const float pre = acc[r] + xd[r] + 0.1f * nz[r];
            hreg[r] = 0.9f * hreg[r] + 0.1f * fmaxf(pre, 0.f);
        }

        // ---- publish h(t): tagged pairs, fire-and-forget (no drain) ----
        const unsigned tagbit = (unsigned)((t >> 1) & 1) << 15;
        unsigned* hdst32 = (unsigned*)(hxg + pb * (NB * H_DIM));
#pragma unroll
        for (int r = 0; r < 4; ++r) {
            unsigned self  = f2bf(hreg[r]);
            unsigned other = __shfl_xor(self, 1, 64);
            if (!(l15 & 1))
                AS(hdst32 + (kb * 4 + r) * (H_DIM / 2) + (n >> 1),
                   self | (other << 16) | tagbit);
        }
        asm volatile("" ::: "memory");   // keep publish ahead of hiddens stores

        // ---- hiddens NT stores off the critical path ----
#pragma unroll
        for (int r = 0; r < 4; ++r)
            __builtin_nontemporal_store(
                hreg[r], &hiddens[((size_t)(b0 + kb * 4 + r) * T_LEN + t) * H_DIM + n]);

        __syncthreads();   // bounds intra-block skew (xs/hlds/strd dbuf WAR)
    }
}

// ---------------- output head: logits + softmax ----------------------------
__global__ __launch_bounds__(256)
void out_head(const float* __restrict__ hiddens, const float* __restrict__ Wout,
              float* __restrict__ outs)
{
    __shared__ float wlds[O_DIM][H_DIM];   // 32 KB
    const int tid = threadIdx.x;
    for (int j = tid; j < (O_DIM * H_DIM) / 4; j += 256)
        ((float4*)wlds)[j] = ((const float4*)Wout)[j];
    __syncthreads();

    const int wave = tid >> 6, lane = tid & 63;
#pragma unroll
    for (int rr = 0; rr < 2; ++rr) {
        const size_t row = (size_t)blockIdx.x * 8 + wave * 2 + rr;  // < 102400
        const float* hp = hiddens + row * H_DIM;

        float a0=0,a1=0,a2=0,a3=0,a4=0,a5=0,a6=0,a7=0;
#pragma unroll
        for (int j = 0; j < 4; ++j) {
            float4 hv = *(const float4*)(hp + lane * 4 + j * 256);
#define DOT(o, acc) { float4 wv = *(const float4*)&wlds[o][lane*4 + j*256]; \
                      acc += hv.x*wv.x + hv.y*wv.y + hv.z*wv.z + hv.w*wv.w; }
            DOT(0,a0) DOT(1,a1) DOT(2,a2) DOT(3,a3)
            DOT(4,a4) DOT(5,a5) DOT(6,a6) DOT(7,a7)
#undef DOT
        }
#pragma unroll
        for (int off = 32; off; off >>= 1) {
            a0 += __shfl_xor(a0, off, 64); a1 += __shfl_xor(a1, off, 64);
            a2 += __shfl_xor(a2, off, 64); a3 += __shfl_xor(a3, off, 64);
            a4 += __shfl_xor(a4, off, 64); a5 += __shfl_xor(a5, off, 64);
            a6 += __shfl_xor(a6, off, 64); a7 += __shfl_xor(a7, off, 64);
        }
        if (lane == 0) {
            float mx = fmaxf(fmaxf(fmaxf(a0,a1),fmaxf(a2,a3)),
                             fmaxf(fmaxf(a4,a5),fmaxf(a6,a7)));
            float e0=expf(a0-mx), e1=expf(a1-mx), e2=expf(a2-mx), e3=expf(a3-mx);
            float e4=expf(a4-mx), e5=expf(a5-mx), e6=expf(a6-mx), e7=expf(a7-mx);
            float inv = 1.f / (e0+e1+e2+e3+e4+e5+e6+e7);
            float* op = outs + row * O_DIM;
            op[0]=e0*inv; op[1]=e1*inv; op[2]=e2*inv; op[3]=e3*inv;
            op[4]=e4*inv; op[5]=e5*inv; op[6]=e6*inv; op[7]=e7*inv;
        }
    }
}

extern "C" void kernel_launch(void* const* d_in, const int* in_sizes, int n_in,
                              void* d_out, int out_size, void* d_ws, size_t ws_size,
                              hipStream_t stream) {
    const float* x     = (const float*)d_in[0];   // [128][800][9]
    const float* noise = (const float*)d_in[1];   // [128][800][1024]
    const float* Win   = (const float*)d_in[2];   // [1024][9]
    const float* Wrec  = (const float*)d_in[3];   // [1024][1024]
    const float* Wout  = (const float*)d_in[4];   // [8][1024]

    float* hiddens = (float*)d_out;                                // 104857600 f32
    float* outs    = hiddens + (size_t)B_TOT * T_LEN * H_DIM;      // 819200 f32

    // ws: [0, 512KB) tagged bf16 h exchange double-buffer. No memset needed:
    // tag parity self-validates across launches/replays (t=0 rewrites buf0
    // before any consumer can accept it; stale tags always mismatch).
    unsigned short* hx = (unsigned short*)d_ws;

    rnn_scan<<<GROUPS * NSLC, 512, 0, stream>>>(x, noise, Win, Wrec, hx, hiddens);
    out_head<<<(B_TOT * T_LEN) / 8, 256, 0, stream>>>(hiddens, Wout, outs);
}